// Round 3
// baseline (359.987 us; speedup 1.0000x reference)
//
#include <hip/hip_runtime.h>

typedef unsigned short u16;
typedef __attribute__((ext_vector_type(4))) float f32x4;
typedef __attribute__((ext_vector_type(8))) short bf16x8;
typedef __attribute__((ext_vector_type(8))) u16 u16x8;
typedef __attribute__((ext_vector_type(4))) u16 u16x4v;

#define DI __device__ __forceinline__

DI u16 f2bf(float f) {
  unsigned int x = __float_as_uint(f);
  unsigned int r = (x + 0x7fffu + ((x >> 16) & 1u)) >> 16;
  return (u16)r;
}
DI float bf2f(u16 u) { return __uint_as_float(((unsigned int)u) << 16); }

// ---------------------------------------------------------------------------
// K0: pack weights. wqkvT[768][256] bf16 (row c = column c of [q|k*s|v]),
// bias[768] fp32 (k part pre-scaled), owT[256][256] bf16 (row c = col c of out_w)
// ---------------------------------------------------------------------------
__global__ __launch_bounds__(256) void pack_kernel(
    const float* __restrict__ qw, const float* __restrict__ qb,
    const float* __restrict__ kw, const float* __restrict__ kb,
    const float* __restrict__ vw, const float* __restrict__ vb,
    const float* __restrict__ ow,
    u16* __restrict__ wqkvT, float* __restrict__ bias, u16* __restrict__ owT)
{
  const int r = blockIdx.x;   // 0..1023
  const int t = threadIdx.x;  // 0..255
  if (r < 768) {
    const int p = r >> 8, c = r & 255;
    const float* wsrc = p == 0 ? qw : (p == 1 ? kw : vw);
    const float sc = (p == 1) ? 0.17677669529663687f : 1.0f;  // 1/sqrt(32)
    wqkvT[r * 256 + t] = f2bf(wsrc[t * 256 + c] * sc);
    if (t == 0) {
      const float* bs = p == 0 ? qb : (p == 1 ? kb : vb);
      bias[r] = bs[c] * sc;
    }
  } else {
    const int c = r - 768;
    owT[c * 256 + t] = f2bf(ow[t * 256 + c]);
  }
}

// ---------------------------------------------------------------------------
// K1a: x fp32 -> bf16, stored TILE-SWIZZLED so that a linear global_load_lds
// copy of one 128x256 tile produces an LDS image whose ds_read_b128
// A-fragment reads are bank-conflict-friendly.
// ---------------------------------------------------------------------------
__global__ __launch_bounds__(256) void convert_kernel(
    const float* __restrict__ x, u16* __restrict__ xb)
{
  const int idx = blockIdx.x * 256 + threadIdx.x;  // 0..2097151
  const int tile = idx >> 12;        // 4096 chunks of 16B per 64KB tile
  const int within = idx & 4095;
  const int r = within >> 5;         // 32 chunks per 512B row
  const int bc = (within & 31) << 4;
  const int sbc = bc ^ ((r & 7) << 4);
  const int row = (tile << 7) + r;
  const float* sp = x + row * 256 + (sbc >> 1);
  const float4 a = *reinterpret_cast<const float4*>(sp);
  const float4 b = *reinterpret_cast<const float4*>(sp + 4);
  u16x8 o;
  o[0] = f2bf(a.x); o[1] = f2bf(a.y); o[2] = f2bf(a.z); o[3] = f2bf(a.w);
  o[4] = f2bf(b.x); o[5] = f2bf(b.y); o[6] = f2bf(b.z); o[7] = f2bf(b.w);
  *reinterpret_cast<u16x8*>(xb + (idx << 3)) = o;
}

// ---------------------------------------------------------------------------
// K1b: QKV projection + bias + RoPE. Grid 512: one block per 128-row tile,
// stages the full 128x256 A-tile ONCE (64 KB LDS, global_load_lds from the
// pre-swizzled source), then loops over all 6 column groups (768 cols).
// ---------------------------------------------------------------------------
__global__ __launch_bounds__(256, 2) void qkv_gemm_kernel(
    const u16* __restrict__ xb, const u16* __restrict__ wT, const float* __restrict__ bias,
    const float* __restrict__ sinp, const float* __restrict__ cosp,
    u16* __restrict__ qr, u16* __restrict__ kr, u16* __restrict__ v)
{
  __shared__ u16 As[32768];  // 64 KB, swizzled image of a 128x256 bf16 tile
  const int t = threadIdx.x;
  const int wave = t >> 6, lane = t & 63;
  const int g = lane >> 4, lr = lane & 15;
  const int wr = wave >> 1, wc = wave & 1;
  const int m0 = blockIdx.x * 128;

  {
    const u16* src = xb + (size_t)blockIdx.x * 32768;
    auto gsrc = (const __attribute__((address_space(1))) u16*)src;
    auto lds = (__attribute__((address_space(3))) u16*)As;
#pragma unroll
    for (int i = 0; i < 16; ++i) {
      const int o = wave * 8192 + i * 512;  // u16 units; 1 KB per call
      __builtin_amdgcn_global_load_lds(
          (const __attribute__((address_space(1))) void*)(gsrc + o + lane * 8),
          (__attribute__((address_space(3))) void*)(lds + o), 16, 0, 0);
    }
  }
  __syncthreads();

  const char* Ab = (const char*)As;
  for (int cg = 0; cg < 6; ++cg) {
    const int c0 = cg * 128;
    f32x4 acc[4][4];
#pragma unroll
    for (int i = 0; i < 4; ++i)
#pragma unroll
      for (int j = 0; j < 4; ++j) acc[i][j] = (f32x4){0.f, 0.f, 0.f, 0.f};

#pragma unroll
    for (int ks = 0; ks < 8; ++ks) {
      bf16x8 af[4], bfr[4];
#pragma unroll
      for (int mt = 0; mt < 4; ++mt) {
        const int rr = wr * 64 + mt * 16 + lr;
        const int cb = (ks * 64 + g * 16) ^ ((rr & 7) << 4);
        af[mt] = *reinterpret_cast<const bf16x8*>(Ab + rr * 512 + cb);
      }
#pragma unroll
      for (int nt = 0; nt < 4; ++nt)
        bfr[nt] = *reinterpret_cast<const bf16x8*>(wT + (c0 + wc * 64 + nt * 16 + lr) * 256 + ks * 32 + g * 8);
#pragma unroll
      for (int mt = 0; mt < 4; ++mt)
#pragma unroll
        for (int nt = 0; nt < 4; ++nt)
          acc[mt][nt] = __builtin_amdgcn_mfma_f32_16x16x32_bf16(af[mt], bfr[nt], acc[mt][nt], 0, 0, 0);
    }

    const int colb = c0 + wc * 64;
    const int proj = colb >> 8;  // 0=q 1=k 2=v (uniform per wave)
    u16* dst = proj == 0 ? qr : (proj == 1 ? kr : v);
#pragma unroll
    for (int mt = 0; mt < 4; ++mt) {
#pragma unroll
      for (int nt = 0; nt < 4; ++nt) {
        const int col = colb + nt * 16 + lr;
        const int e = col & 255;
        const float bc2 = bias[col];
#pragma unroll
        for (int j = 0; j < 4; ++j) {
          const int tok = m0 + wr * 64 + mt * 16 + g * 4 + j;
          const float val = acc[mt][nt][j] + bc2;
          float res;
          if (proj < 2) {
            // rotate_every_two: partner column (col^1) lives in lane^1, same slot.
            const float partner = __shfl_xor(val, 1);
            const int d = e & 31;
            const int pos = tok & 4095;  // h*64 + w
            const float sn = sinp[pos * 32 + d];
            const float cs = cosp[pos * 32 + d];
            const float rot = (d & 1) ? partner : -partner;
            res = val * cs + rot * sn;
          } else {
            res = val;
          }
          dst[tok * 256 + e] = f2bf(res);
        }
      }
    }
  }
}

// ---------------------------------------------------------------------------
// K2/K3: axial attention. mode 0: over W (block = (b,h), token stride 256).
//        mode 1: over H (block = (b,w), token stride 16384).
// ---------------------------------------------------------------------------
__global__ __launch_bounds__(256, 2) void attn_kernel(
    const u16* __restrict__ qr, const u16* __restrict__ kr, const u16* __restrict__ vsrc,
    const float* __restrict__ mask, u16* __restrict__ dst, const int mode)
{
  __shared__ u16 Pbuf[4][64][72];
  __shared__ u16 Vs[64][260];
  const int t = threadIdx.x;
  const int wave = t >> 6, lane = t & 63;
  const int g = lane >> 4, lr = lane & 15;
  const int b = blockIdx.x >> 6, o = blockIdx.x & 63;
  const int base = (mode == 0) ? (b * 4096 + o * 64) * 256 : (b * 4096 + o) * 256;
  const int ts = (mode == 0) ? 256 : 16384;

#pragma unroll
  for (int i = 0; i < 16; ++i) {
    const int idx = t + 256 * i;
    const int tok = idx >> 6, c4 = (idx & 63) << 2;
    *reinterpret_cast<u16x4v*>(&Vs[tok][c4]) =
        *reinterpret_cast<const u16x4v*>(vsrc + base + tok * ts + c4);
  }
  __syncthreads();

  for (int hh = 0; hh < 2; ++hh) {
    const int n = wave * 2 + hh;
    bf16x8 qf[4], kf[4];
#pragma unroll
    for (int mt = 0; mt < 4; ++mt) {
      qf[mt] = *reinterpret_cast<const bf16x8*>(qr + base + (mt * 16 + lr) * ts + n * 32 + g * 8);
      kf[mt] = *reinterpret_cast<const bf16x8*>(kr + base + (mt * 16 + lr) * ts + n * 32 + g * 8);
    }
    const f32x4 zero = (f32x4){0.f, 0.f, 0.f, 0.f};
    f32x4 s[4][4];
#pragma unroll
    for (int mt = 0; mt < 4; ++mt)
#pragma unroll
      for (int nt = 0; nt < 4; ++nt)
        s[mt][nt] = __builtin_amdgcn_mfma_f32_16x16x32_bf16(qf[mt], kf[nt], zero, 0, 0, 0);

    const float* mp = mask + n * 4096;
#pragma unroll
    for (int mt = 0; mt < 4; ++mt) {
#pragma unroll
      for (int j = 0; j < 4; ++j) {
        const int r = mt * 16 + g * 4 + j;
#pragma unroll
        for (int nt = 0; nt < 4; ++nt)
          s[mt][nt][j] += mp[r * 64 + nt * 16 + lr];
        float m = fmaxf(fmaxf(s[mt][0][j], s[mt][1][j]), fmaxf(s[mt][2][j], s[mt][3][j]));
        m = fmaxf(m, __shfl_xor(m, 1));
        m = fmaxf(m, __shfl_xor(m, 2));
        m = fmaxf(m, __shfl_xor(m, 4));
        m = fmaxf(m, __shfl_xor(m, 8));
        float sum = 0.f;
#pragma unroll
        for (int nt = 0; nt < 4; ++nt) {
          const float p = __expf(s[mt][nt][j] - m);
          s[mt][nt][j] = p;
          sum += p;
        }
        sum += __shfl_xor(sum, 1);
        sum += __shfl_xor(sum, 2);
        sum += __shfl_xor(sum, 4);
        sum += __shfl_xor(sum, 8);
        const float rs = 1.f / sum;
#pragma unroll
        for (int nt = 0; nt < 4; ++nt)
          Pbuf[wave][r][nt * 16 + lr] = f2bf(s[mt][nt][j] * rs);
      }
    }
    __syncthreads();

    f32x4 oacc[4][2];
#pragma unroll
    for (int mt = 0; mt < 4; ++mt)
#pragma unroll
      for (int nd = 0; nd < 2; ++nd) oacc[mt][nd] = zero;

#pragma unroll
    for (int kt = 0; kt < 2; ++kt) {
      bf16x8 pa[4];
#pragma unroll
      for (int mt = 0; mt < 4; ++mt)
        pa[mt] = *reinterpret_cast<const bf16x8*>(&Pbuf[wave][mt * 16 + lr][kt * 32 + g * 8]);
#pragma unroll
      for (int nd = 0; nd < 2; ++nd) {
        const int dcol = n * 32 + nd * 16 + lr;
        bf16x8 vb;
#pragma unroll
        for (int j2 = 0; j2 < 8; ++j2)
          vb[j2] = (short)Vs[kt * 32 + g * 8 + j2][dcol];
#pragma unroll
        for (int mt = 0; mt < 4; ++mt)
          oacc[mt][nd] = __builtin_amdgcn_mfma_f32_16x16x32_bf16(pa[mt], vb, oacc[mt][nd], 0, 0, 0);
      }
    }
#pragma unroll
    for (int mt = 0; mt < 4; ++mt)
#pragma unroll
      for (int nd = 0; nd < 2; ++nd)
#pragma unroll
        for (int j = 0; j < 4; ++j)
          dst[base + (mt * 16 + g * 4 + j) * ts + n * 32 + nd * 16 + lr] = f2bf(oacc[mt][nd][j]);
    __syncthreads();
  }
}

// ---------------------------------------------------------------------------
// K4: depthwise 5x5 conv (LePE). thread = 1 pixel x 8 channels.
// ---------------------------------------------------------------------------
__global__ __launch_bounds__(256) void lepe_kernel(
    const u16* __restrict__ v, const float* __restrict__ cw, const float* __restrict__ cb,
    u16* __restrict__ lepe)
{
  const int t = threadIdx.x;
  const int pix = blockIdx.x * 8 + (t >> 5);
  const int c0 = (t & 31) * 8;
  const int b = pix >> 12, hw = pix & 4095, h = hw >> 6, w = hw & 63;
  float acc[8];
#pragma unroll
  for (int j = 0; j < 8; ++j) acc[j] = cb[c0 + j];
  for (int dy = 0; dy < 5; ++dy) {
    const int hh = h + dy - 2;
    if ((unsigned)hh >= 64u) continue;
    for (int dx = 0; dx < 5; ++dx) {
      const int ww = w + dx - 2;
      if ((unsigned)ww >= 64u) continue;
      const u16x8 vv = *reinterpret_cast<const u16x8*>(v + ((b * 64 + hh) * 64 + ww) * 256 + c0);
      const float* wp = cw + (dy * 5 + dx) * 256 + c0;
      const float4 w0 = *reinterpret_cast<const float4*>(wp);
      const float4 w1 = *reinterpret_cast<const float4*>(wp + 4);
      acc[0] += bf2f(vv[0]) * w0.x;
      acc[1] += bf2f(vv[1]) * w0.y;
      acc[2] += bf2f(vv[2]) * w0.z;
      acc[3] += bf2f(vv[3]) * w0.w;
      acc[4] += bf2f(vv[4]) * w1.x;
      acc[5] += bf2f(vv[5]) * w1.y;
      acc[6] += bf2f(vv[6]) * w1.z;
      acc[7] += bf2f(vv[7]) * w1.w;
    }
  }
  u16x8 r;
#pragma unroll
  for (int j = 0; j < 8; ++j) r[j] = f2bf(acc[j]);
  *reinterpret_cast<u16x8*>(lepe + pix * 256 + c0) = r;
}

// ---------------------------------------------------------------------------
// K5: out = (attn_out + lepe) @ out_w + out_b. Grid 512: stage the fused
// 128x256 A-tile once (swizzled ds_write), loop both 128-col groups.
// ---------------------------------------------------------------------------
__global__ __launch_bounds__(256, 2) void out_gemm_kernel(
    const u16* __restrict__ ao, const u16* __restrict__ lep, const u16* __restrict__ owT,
    const float* __restrict__ ob, float* __restrict__ out)
{
  __shared__ u16 As[32768];
  const int t = threadIdx.x;
  const int wave = t >> 6, lane = t & 63;
  const int g = lane >> 4, lr = lane & 15;
  const int wr = wave >> 1, wc = wave & 1;
  const int m0 = blockIdx.x * 128;

  char* Abw = (char*)As;
#pragma unroll
  for (int i = 0; i < 16; ++i) {
    const int idx = t + 256 * i;        // 16B chunk index
    const int r = idx >> 5;
    const int bc = (idx & 31) << 4;
    const int off = (m0 + r) * 256 + (bc >> 1);
    const u16x8 a = *reinterpret_cast<const u16x8*>(ao + off);
    const u16x8 l = *reinterpret_cast<const u16x8*>(lep + off);
    u16x8 s;
#pragma unroll
    for (int j = 0; j < 8; ++j) s[j] = f2bf(bf2f(a[j]) + bf2f(l[j]));
    *reinterpret_cast<u16x8*>(Abw + r * 512 + (bc ^ ((r & 7) << 4))) = s;
  }
  __syncthreads();

  const char* Ab = (const char*)As;
  for (int cg = 0; cg < 2; ++cg) {
    const int c0 = cg * 128;
    f32x4 acc[4][4];
#pragma unroll
    for (int i = 0; i < 4; ++i)
#pragma unroll
      for (int j = 0; j < 4; ++j) acc[i][j] = (f32x4){0.f, 0.f, 0.f, 0.f};

#pragma unroll
    for (int ks = 0; ks < 8; ++ks) {
      bf16x8 af[4], bfr[4];
#pragma unroll
      for (int mt = 0; mt < 4; ++mt) {
        const int rr = wr * 64 + mt * 16 + lr;
        const int cb = (ks * 64 + g * 16) ^ ((rr & 7) << 4);
        af[mt] = *reinterpret_cast<const bf16x8*>(Ab + rr * 512 + cb);
      }
#pragma unroll
      for (int nt = 0; nt < 4; ++nt)
        bfr[nt] = *reinterpret_cast<const bf16x8*>(owT + (c0 + wc * 64 + nt * 16 + lr) * 256 + ks * 32 + g * 8);
#pragma unroll
      for (int mt = 0; mt < 4; ++mt)
#pragma unroll
        for (int nt = 0; nt < 4; ++nt)
          acc[mt][nt] = __builtin_amdgcn_mfma_f32_16x16x32_bf16(af[mt], bfr[nt], acc[mt][nt], 0, 0, 0);
    }

#pragma unroll
    for (int mt = 0; mt < 4; ++mt) {
#pragma unroll
      for (int nt = 0; nt < 4; ++nt) {
        const int col = c0 + wc * 64 + nt * 16 + lr;
        const float bc2 = ob[col];
#pragma unroll
        for (int j = 0; j < 4; ++j) {
          const int tok = m0 + wr * 64 + mt * 16 + g * 4 + j;
          out[tok * 256 + col] = acc[mt][nt][j] + bc2;
        }
      }
    }
  }
}

// ---------------------------------------------------------------------------
extern "C" void kernel_launch(void* const* d_in, const int* in_sizes, int n_in,
                              void* d_out, int out_size, void* d_ws, size_t ws_size,
                              hipStream_t stream)
{
  const float* x      = (const float*)d_in[0];
  const float* sinp   = (const float*)d_in[1];
  const float* cosp   = (const float*)d_in[2];
  const float* mask_h = (const float*)d_in[3];
  const float* mask_w = (const float*)d_in[4];
  const float* q_w    = (const float*)d_in[5];
  const float* q_b    = (const float*)d_in[6];
  const float* k_w    = (const float*)d_in[7];
  const float* k_b    = (const float*)d_in[8];
  const float* v_w    = (const float*)d_in[9];
  const float* v_b    = (const float*)d_in[10];
  const float* lepe_w = (const float*)d_in[11];
  const float* lepe_b = (const float*)d_in[12];
  const float* out_w  = (const float*)d_in[13];
  const float* out_b  = (const float*)d_in[14];

  unsigned char* ws = (unsigned char*)d_ws;
  const size_t SZ = 33554432;  // 65536*256*2 bytes
  u16* qr    = (u16*)(ws);
  u16* kr    = (u16*)(ws + SZ);
  u16* vv    = (u16*)(ws + 2 * SZ);
  u16* v1    = (u16*)(ws + 3 * SZ);
  u16* xb    = (u16*)(ws + 4 * SZ);  // x as swizzled bf16; dead after qkv_gemm
  u16* lepe  = (u16*)(ws + 4 * SZ);  // reuses xb slot (written after qkv_gemm)
  u16* wqkvT = (u16*)(ws + 5 * SZ);
  u16* owT   = (u16*)(ws + 5 * SZ + 393216);
  float* bias = (float*)(ws + 5 * SZ + 393216 + 131072);
  u16* attn_out = vv;  // v is dead after conv + attnW

  pack_kernel<<<1024, 256, 0, stream>>>(q_w, q_b, k_w, k_b, v_w, v_b, out_w, wqkvT, bias, owT);
  convert_kernel<<<8192, 256, 0, stream>>>(x, xb);
  qkv_gemm_kernel<<<512, 256, 0, stream>>>(xb, wqkvT, bias, sinp, cosp, qr, kr, vv);
  lepe_kernel<<<8192, 256, 0, stream>>>(vv, lepe_w, lepe_b, lepe);
  attn_kernel<<<1024, 256, 0, stream>>>(qr, kr, vv, mask_w, v1, 0);
  attn_kernel<<<1024, 256, 0, stream>>>(qr, kr, v1, mask_h, attn_out, 1);
  out_gemm_kernel<<<512, 256, 0, stream>>>(attn_out, lepe, owT, out_b, (float*)d_out);
}

// Round 4
// 289.580 us; speedup vs baseline: 1.2431x; 1.2431x over previous
//
#include <hip/hip_runtime.h>

typedef unsigned short u16;
typedef __attribute__((ext_vector_type(4))) float f32x4;
typedef __attribute__((ext_vector_type(8))) short bf16x8;
typedef __attribute__((ext_vector_type(8))) u16 u16x8;
typedef __attribute__((ext_vector_type(4))) u16 u16x4v;

#define DI __device__ __forceinline__

DI u16 f2bf(float f) {
  unsigned int x = __float_as_uint(f);
  unsigned int r = (x + 0x7fffu + ((x >> 16) & 1u)) >> 16;
  return (u16)r;
}
DI float bf2f(u16 u) { return __uint_as_float(((unsigned int)u) << 16); }

// ---------------------------------------------------------------------------
// K0: pack weights. wqkvT[768][256] bf16 (row c = column c of [q|k*s|v]),
// bias[768] fp32 (k part pre-scaled), owT[256][256] bf16 (row c = col c of out_w)
// ---------------------------------------------------------------------------
__global__ __launch_bounds__(256) void pack_kernel(
    const float* __restrict__ qw, const float* __restrict__ qb,
    const float* __restrict__ kw, const float* __restrict__ kb,
    const float* __restrict__ vw, const float* __restrict__ vb,
    const float* __restrict__ ow,
    u16* __restrict__ wqkvT, float* __restrict__ bias, u16* __restrict__ owT)
{
  const int r = blockIdx.x;   // 0..1023
  const int t = threadIdx.x;  // 0..255
  if (r < 768) {
    const int p = r >> 8, c = r & 255;
    const float* wsrc = p == 0 ? qw : (p == 1 ? kw : vw);
    const float sc = (p == 1) ? 0.17677669529663687f : 1.0f;  // 1/sqrt(32)
    wqkvT[r * 256 + t] = f2bf(wsrc[t * 256 + c] * sc);
    if (t == 0) {
      const float* bs = p == 0 ? qb : (p == 1 ? kb : vb);
      bias[r] = bs[c] * sc;
    }
  } else {
    const int c = r - 768;
    owT[c * 256 + t] = f2bf(ow[t * 256 + c]);
  }
}

// ---------------------------------------------------------------------------
// K1a: x fp32 -> bf16, stored TILE-SWIZZLED so that a linear global_load_lds
// copy of one 128x256 tile produces an LDS image whose ds_read_b128
// A-fragment reads are bank-conflict-friendly.
// ---------------------------------------------------------------------------
__global__ __launch_bounds__(256) void convert_kernel(
    const float* __restrict__ x, u16* __restrict__ xb)
{
  const int idx = blockIdx.x * 256 + threadIdx.x;  // 0..2097151
  const int tile = idx >> 12;        // 4096 chunks of 16B per 64KB tile
  const int within = idx & 4095;
  const int r = within >> 5;         // 32 chunks per 512B row
  const int bc = (within & 31) << 4;
  const int sbc = bc ^ ((r & 7) << 4);
  const int row = (tile << 7) + r;
  const float* sp = x + row * 256 + (sbc >> 1);
  const float4 a = *reinterpret_cast<const float4*>(sp);
  const float4 b = *reinterpret_cast<const float4*>(sp + 4);
  u16x8 o;
  o[0] = f2bf(a.x); o[1] = f2bf(a.y); o[2] = f2bf(a.z); o[3] = f2bf(a.w);
  o[4] = f2bf(b.x); o[5] = f2bf(b.y); o[6] = f2bf(b.z); o[7] = f2bf(b.w);
  *reinterpret_cast<u16x8*>(xb + (idx << 3)) = o;
}

// ---------------------------------------------------------------------------
// K1b: QKV projection + bias + RoPE. Grid 512: one block per 128-row tile,
// stages the full 128x256 A-tile ONCE (64 KB LDS via global_load_lds from the
// pre-swizzled source), loops over 6 column groups. Epilogue transposes each
// wave's 16x64 output slab through a per-wave LDS buffer so each lane owns 8
// CONSECUTIVE columns: RoPE pairs are in-lane (no shfl), sin/cos are 16B
// vector loads, and stores are 16B bf16x8 (coalesced).
// ---------------------------------------------------------------------------
__global__ __launch_bounds__(256, 2) void qkv_gemm_kernel(
    const u16* __restrict__ xb, const u16* __restrict__ wT, const float* __restrict__ bias,
    const float* __restrict__ sinp, const float* __restrict__ cosp,
    u16* __restrict__ qr, u16* __restrict__ kr, u16* __restrict__ v)
{
  __shared__ u16 As[32768];        // 64 KB swizzled A-tile
  __shared__ float Tr[4][1024];    // 16 KB: per-wave 16x64 transpose slab (stride 64, g-XOR swizzle)
  const int t = threadIdx.x;
  const int wave = t >> 6, lane = t & 63;
  const int g = lane >> 4, lr = lane & 15;
  const int wr = wave >> 1, wc = wave & 1;
  const int m0 = blockIdx.x * 128;

  {
    const u16* src = xb + (size_t)blockIdx.x * 32768;
    auto gsrc = (const __attribute__((address_space(1))) u16*)src;
    auto lds = (__attribute__((address_space(3))) u16*)As;
#pragma unroll
    for (int i = 0; i < 16; ++i) {
      const int o = wave * 8192 + i * 512;  // u16 units; 1 KB per call
      __builtin_amdgcn_global_load_lds(
          (const __attribute__((address_space(1))) void*)(gsrc + o + lane * 8),
          (__attribute__((address_space(3))) void*)(lds + o), 16, 0, 0);
    }
  }
  __syncthreads();

  const char* Ab = (const char*)As;
  float* Trw = Tr[wave];
  const int tl = (lane >> 3);        // 0..7: token sub-row for epilogue reads
  const int cg8 = (lane & 7) * 8;    // 0..56: column chunk for epilogue reads

  for (int cg = 0; cg < 6; ++cg) {
    const int c0 = cg * 128;
    f32x4 acc[4][4];
#pragma unroll
    for (int i = 0; i < 4; ++i)
#pragma unroll
      for (int j = 0; j < 4; ++j) acc[i][j] = (f32x4){0.f, 0.f, 0.f, 0.f};

#pragma unroll
    for (int ks = 0; ks < 8; ++ks) {
      bf16x8 af[4], bfr[4];
#pragma unroll
      for (int mt = 0; mt < 4; ++mt) {
        const int rr = wr * 64 + mt * 16 + lr;
        const int cb = (ks * 64 + g * 16) ^ ((rr & 7) << 4);
        af[mt] = *reinterpret_cast<const bf16x8*>(Ab + rr * 512 + cb);
      }
#pragma unroll
      for (int nt = 0; nt < 4; ++nt)
        bfr[nt] = *reinterpret_cast<const bf16x8*>(wT + (c0 + wc * 64 + nt * 16 + lr) * 256 + ks * 32 + g * 8);
#pragma unroll
      for (int mt = 0; mt < 4; ++mt)
#pragma unroll
        for (int nt = 0; nt < 4; ++nt)
          acc[mt][nt] = __builtin_amdgcn_mfma_f32_16x16x32_bf16(af[mt], bfr[nt], acc[mt][nt], 0, 0, 0);
    }

    const int colb = c0 + wc * 64;
    const int proj = colb >> 8;  // 0=q 1=k 2=v (uniform per wave)
    u16* dst = proj == 0 ? qr : (proj == 1 ? kr : v);
    const int e0 = (colb & 255) + cg8;

    float bcv[4];
#pragma unroll
    for (int nt = 0; nt < 4; ++nt) bcv[nt] = bias[colb + nt * 16 + lr];

#pragma unroll
    for (int mt = 0; mt < 4; ++mt) {
      // scatter this wave's 16x64 slab into Tr: row = g*4+j, col = nt*16+lr,
      // col XOR (g<<4) keeps writes 2-way max (free).
#pragma unroll
      for (int nt = 0; nt < 4; ++nt)
#pragma unroll
        for (int j = 0; j < 4; ++j)
          Trw[(g * 4 + j) * 64 + ((nt * 16 + lr) ^ (g << 4))] = acc[mt][nt][j] + bcv[nt];
      asm volatile("s_waitcnt lgkmcnt(0)" ::: "memory");
#pragma unroll
      for (int r2 = 0; r2 < 2; ++r2) {
        const int row = tl + 8 * r2;                    // 0..15
        const int rb = row * 64 + (cg8 ^ ((row >> 2) << 4));
        const float4 v0 = *reinterpret_cast<const float4*>(Trw + rb);
        const float4 v1 = *reinterpret_cast<const float4*>(Trw + rb + 4);
        const int tok = m0 + wr * 64 + mt * 16 + row;
        float r0, r1, r2v, r3, r4, r5, r6, r7;
        if (proj < 2) {
          const int pos = tok & 4095;        // h*64 + w
          const int d0 = cg8 & 31;           // head-dim base (multiple of 8)
          const float* sp2 = sinp + pos * 32 + d0;
          const float* cp2 = cosp + pos * 32 + d0;
          const float4 s0 = *reinterpret_cast<const float4*>(sp2);
          const float4 s1 = *reinterpret_cast<const float4*>(sp2 + 4);
          const float4 cA = *reinterpret_cast<const float4*>(cp2);
          const float4 cB = *reinterpret_cast<const float4*>(cp2 + 4);
          r0  = v0.x * cA.x - v0.y * s0.x;
          r1  = v0.y * cA.y + v0.x * s0.y;
          r2v = v0.z * cA.z - v0.w * s0.z;
          r3  = v0.w * cA.w + v0.z * s0.w;
          r4  = v1.x * cB.x - v1.y * s1.x;
          r5  = v1.y * cB.y + v1.x * s1.y;
          r6  = v1.z * cB.z - v1.w * s1.z;
          r7  = v1.w * cB.w + v1.z * s1.w;
        } else {
          r0 = v0.x; r1 = v0.y; r2v = v0.z; r3 = v0.w;
          r4 = v1.x; r5 = v1.y; r6 = v1.z; r7 = v1.w;
        }
        u16x8 o;
        o[0] = f2bf(r0);  o[1] = f2bf(r1);  o[2] = f2bf(r2v); o[3] = f2bf(r3);
        o[4] = f2bf(r4);  o[5] = f2bf(r5);  o[6] = f2bf(r6);  o[7] = f2bf(r7);
        *reinterpret_cast<u16x8*>(dst + tok * 256 + e0) = o;
      }
      asm volatile("s_waitcnt lgkmcnt(0)" ::: "memory");  // drain before next mt overwrites Tr
    }
  }
}

// ---------------------------------------------------------------------------
// K2/K3: axial attention. mode 0: over W (block = (b,h), token stride 256).
//        mode 1: over H (block = (b,w), token stride 16384).
// ---------------------------------------------------------------------------
__global__ __launch_bounds__(256, 2) void attn_kernel(
    const u16* __restrict__ qr, const u16* __restrict__ kr, const u16* __restrict__ vsrc,
    const float* __restrict__ mask, u16* __restrict__ dst, const int mode)
{
  __shared__ u16 Pbuf[4][64][72];
  __shared__ u16 Vs[64][260];
  const int t = threadIdx.x;
  const int wave = t >> 6, lane = t & 63;
  const int g = lane >> 4, lr = lane & 15;
  const int b = blockIdx.x >> 6, o = blockIdx.x & 63;
  const int base = (mode == 0) ? (b * 4096 + o * 64) * 256 : (b * 4096 + o) * 256;
  const int ts = (mode == 0) ? 256 : 16384;

#pragma unroll
  for (int i = 0; i < 16; ++i) {
    const int idx = t + 256 * i;
    const int tok = idx >> 6, c4 = (idx & 63) << 2;
    *reinterpret_cast<u16x4v*>(&Vs[tok][c4]) =
        *reinterpret_cast<const u16x4v*>(vsrc + base + tok * ts + c4);
  }
  __syncthreads();

  for (int hh = 0; hh < 2; ++hh) {
    const int n = wave * 2 + hh;
    bf16x8 qf[4], kf[4];
#pragma unroll
    for (int mt = 0; mt < 4; ++mt) {
      qf[mt] = *reinterpret_cast<const bf16x8*>(qr + base + (mt * 16 + lr) * ts + n * 32 + g * 8);
      kf[mt] = *reinterpret_cast<const bf16x8*>(kr + base + (mt * 16 + lr) * ts + n * 32 + g * 8);
    }
    const f32x4 zero = (f32x4){0.f, 0.f, 0.f, 0.f};
    f32x4 s[4][4];
#pragma unroll
    for (int mt = 0; mt < 4; ++mt)
#pragma unroll
      for (int nt = 0; nt < 4; ++nt)
        s[mt][nt] = __builtin_amdgcn_mfma_f32_16x16x32_bf16(qf[mt], kf[nt], zero, 0, 0, 0);

    const float* mp = mask + n * 4096;
#pragma unroll
    for (int mt = 0; mt < 4; ++mt) {
#pragma unroll
      for (int j = 0; j < 4; ++j) {
        const int r = mt * 16 + g * 4 + j;
#pragma unroll
        for (int nt = 0; nt < 4; ++nt)
          s[mt][nt][j] += mp[r * 64 + nt * 16 + lr];
        float m = fmaxf(fmaxf(s[mt][0][j], s[mt][1][j]), fmaxf(s[mt][2][j], s[mt][3][j]));
        m = fmaxf(m, __shfl_xor(m, 1));
        m = fmaxf(m, __shfl_xor(m, 2));
        m = fmaxf(m, __shfl_xor(m, 4));
        m = fmaxf(m, __shfl_xor(m, 8));
        float sum = 0.f;
#pragma unroll
        for (int nt = 0; nt < 4; ++nt) {
          const float p = __expf(s[mt][nt][j] - m);
          s[mt][nt][j] = p;
          sum += p;
        }
        sum += __shfl_xor(sum, 1);
        sum += __shfl_xor(sum, 2);
        sum += __shfl_xor(sum, 4);
        sum += __shfl_xor(sum, 8);
        const float rs = 1.f / sum;
#pragma unroll
        for (int nt = 0; nt < 4; ++nt)
          Pbuf[wave][r][nt * 16 + lr] = f2bf(s[mt][nt][j] * rs);
      }
    }
    __syncthreads();

    f32x4 oacc[4][2];
#pragma unroll
    for (int mt = 0; mt < 4; ++mt)
#pragma unroll
      for (int nd = 0; nd < 2; ++nd) oacc[mt][nd] = zero;

#pragma unroll
    for (int kt = 0; kt < 2; ++kt) {
      bf16x8 pa[4];
#pragma unroll
      for (int mt = 0; mt < 4; ++mt)
        pa[mt] = *reinterpret_cast<const bf16x8*>(&Pbuf[wave][mt * 16 + lr][kt * 32 + g * 8]);
#pragma unroll
      for (int nd = 0; nd < 2; ++nd) {
        const int dcol = n * 32 + nd * 16 + lr;
        bf16x8 vb;
#pragma unroll
        for (int j2 = 0; j2 < 8; ++j2)
          vb[j2] = (short)Vs[kt * 32 + g * 8 + j2][dcol];
#pragma unroll
        for (int mt = 0; mt < 4; ++mt)
          oacc[mt][nd] = __builtin_amdgcn_mfma_f32_16x16x32_bf16(pa[mt], vb, oacc[mt][nd], 0, 0, 0);
      }
    }
#pragma unroll
    for (int mt = 0; mt < 4; ++mt)
#pragma unroll
      for (int nd = 0; nd < 2; ++nd)
#pragma unroll
        for (int j = 0; j < 4; ++j)
          dst[base + (mt * 16 + g * 4 + j) * ts + n * 32 + nd * 16 + lr] = f2bf(oacc[mt][nd][j]);
    __syncthreads();
  }
}

// ---------------------------------------------------------------------------
// K4: depthwise 5x5 conv (LePE). thread = 1 pixel x 8 channels.
// ---------------------------------------------------------------------------
__global__ __launch_bounds__(256) void lepe_kernel(
    const u16* __restrict__ v, const float* __restrict__ cw, const float* __restrict__ cb,
    u16* __restrict__ lepe)
{
  const int t = threadIdx.x;
  const int pix = blockIdx.x * 8 + (t >> 5);
  const int c0 = (t & 31) * 8;
  const int b = pix >> 12, hw = pix & 4095, h = hw >> 6, w = hw & 63;
  float acc[8];
#pragma unroll
  for (int j = 0; j < 8; ++j) acc[j] = cb[c0 + j];
  for (int dy = 0; dy < 5; ++dy) {
    const int hh = h + dy - 2;
    if ((unsigned)hh >= 64u) continue;
    for (int dx = 0; dx < 5; ++dx) {
      const int ww = w + dx - 2;
      if ((unsigned)ww >= 64u) continue;
      const u16x8 vv = *reinterpret_cast<const u16x8*>(v + ((b * 64 + hh) * 64 + ww) * 256 + c0);
      const float* wp = cw + (dy * 5 + dx) * 256 + c0;
      const float4 w0 = *reinterpret_cast<const float4*>(wp);
      const float4 w1 = *reinterpret_cast<const float4*>(wp + 4);
      acc[0] += bf2f(vv[0]) * w0.x;
      acc[1] += bf2f(vv[1]) * w0.y;
      acc[2] += bf2f(vv[2]) * w0.z;
      acc[3] += bf2f(vv[3]) * w0.w;
      acc[4] += bf2f(vv[4]) * w1.x;
      acc[5] += bf2f(vv[5]) * w1.y;
      acc[6] += bf2f(vv[6]) * w1.z;
      acc[7] += bf2f(vv[7]) * w1.w;
    }
  }
  u16x8 r;
#pragma unroll
  for (int j = 0; j < 8; ++j) r[j] = f2bf(acc[j]);
  *reinterpret_cast<u16x8*>(lepe + pix * 256 + c0) = r;
}

// ---------------------------------------------------------------------------
// K5: out = (attn_out + lepe) @ out_w + out_b. Grid 512: stage the fused
// 128x256 A-tile once (swizzled ds_write), loop both 128-col groups.
// ---------------------------------------------------------------------------
__global__ __launch_bounds__(256, 2) void out_gemm_kernel(
    const u16* __restrict__ ao, const u16* __restrict__ lep, const u16* __restrict__ owT,
    const float* __restrict__ ob, float* __restrict__ out)
{
  __shared__ u16 As[32768];
  const int t = threadIdx.x;
  const int wave = t >> 6, lane = t & 63;
  const int g = lane >> 4, lr = lane & 15;
  const int wr = wave >> 1, wc = wave & 1;
  const int m0 = blockIdx.x * 128;

  char* Abw = (char*)As;
#pragma unroll
  for (int i = 0; i < 16; ++i) {
    const int idx = t + 256 * i;        // 16B chunk index
    const int r = idx >> 5;
    const int bc = (idx & 31) << 4;
    const int off = (m0 + r) * 256 + (bc >> 1);
    const u16x8 a = *reinterpret_cast<const u16x8*>(ao + off);
    const u16x8 l = *reinterpret_cast<const u16x8*>(lep + off);
    u16x8 s;
#pragma unroll
    for (int j = 0; j < 8; ++j) s[j] = f2bf(bf2f(a[j]) + bf2f(l[j]));
    *reinterpret_cast<u16x8*>(Abw + r * 512 + (bc ^ ((r & 7) << 4))) = s;
  }
  __syncthreads();

  const char* Ab = (const char*)As;
  for (int cg = 0; cg < 2; ++cg) {
    const int c0 = cg * 128;
    f32x4 acc[4][4];
#pragma unroll
    for (int i = 0; i < 4; ++i)
#pragma unroll
      for (int j = 0; j < 4; ++j) acc[i][j] = (f32x4){0.f, 0.f, 0.f, 0.f};

#pragma unroll
    for (int ks = 0; ks < 8; ++ks) {
      bf16x8 af[4], bfr[4];
#pragma unroll
      for (int mt = 0; mt < 4; ++mt) {
        const int rr = wr * 64 + mt * 16 + lr;
        const int cb = (ks * 64 + g * 16) ^ ((rr & 7) << 4);
        af[mt] = *reinterpret_cast<const bf16x8*>(Ab + rr * 512 + cb);
      }
#pragma unroll
      for (int nt = 0; nt < 4; ++nt)
        bfr[nt] = *reinterpret_cast<const bf16x8*>(owT + (c0 + wc * 64 + nt * 16 + lr) * 256 + ks * 32 + g * 8);
#pragma unroll
      for (int mt = 0; mt < 4; ++mt)
#pragma unroll
        for (int nt = 0; nt < 4; ++nt)
          acc[mt][nt] = __builtin_amdgcn_mfma_f32_16x16x32_bf16(af[mt], bfr[nt], acc[mt][nt], 0, 0, 0);
    }

#pragma unroll
    for (int mt = 0; mt < 4; ++mt) {
#pragma unroll
      for (int nt = 0; nt < 4; ++nt) {
        const int col = c0 + wc * 64 + nt * 16 + lr;
        const float bc2 = ob[col];
#pragma unroll
        for (int j = 0; j < 4; ++j) {
          const int tok = m0 + wr * 64 + mt * 16 + g * 4 + j;
          out[tok * 256 + col] = acc[mt][nt][j] + bc2;
        }
      }
    }
  }
}

// ---------------------------------------------------------------------------
extern "C" void kernel_launch(void* const* d_in, const int* in_sizes, int n_in,
                              void* d_out, int out_size, void* d_ws, size_t ws_size,
                              hipStream_t stream)
{
  const float* x      = (const float*)d_in[0];
  const float* sinp   = (const float*)d_in[1];
  const float* cosp   = (const float*)d_in[2];
  const float* mask_h = (const float*)d_in[3];
  const float* mask_w = (const float*)d_in[4];
  const float* q_w    = (const float*)d_in[5];
  const float* q_b    = (const float*)d_in[6];
  const float* k_w    = (const float*)d_in[7];
  const float* k_b    = (const float*)d_in[8];
  const float* v_w    = (const float*)d_in[9];
  const float* v_b    = (const float*)d_in[10];
  const float* lepe_w = (const float*)d_in[11];
  const float* lepe_b = (const float*)d_in[12];
  const float* out_w  = (const float*)d_in[13];
  const float* out_b  = (const float*)d_in[14];

  unsigned char* ws = (unsigned char*)d_ws;
  const size_t SZ = 33554432;  // 65536*256*2 bytes
  u16* qr    = (u16*)(ws);
  u16* kr    = (u16*)(ws + SZ);
  u16* vv    = (u16*)(ws + 2 * SZ);
  u16* v1    = (u16*)(ws + 3 * SZ);
  u16* xb    = (u16*)(ws + 4 * SZ);  // x as swizzled bf16; dead after qkv_gemm
  u16* lepe  = (u16*)(ws + 4 * SZ);  // reuses xb slot (written after qkv_gemm)
  u16* wqkvT = (u16*)(ws + 5 * SZ);
  u16* owT   = (u16*)(ws + 5 * SZ + 393216);
  float* bias = (float*)(ws + 5 * SZ + 393216 + 131072);
  u16* attn_out = vv;  // v is dead after conv + attnW

  pack_kernel<<<1024, 256, 0, stream>>>(q_w, q_b, k_w, k_b, v_w, v_b, out_w, wqkvT, bias, owT);
  convert_kernel<<<8192, 256, 0, stream>>>(x, xb);
  qkv_gemm_kernel<<<512, 256, 0, stream>>>(xb, wqkvT, bias, sinp, cosp, qr, kr, vv);
  lepe_kernel<<<8192, 256, 0, stream>>>(vv, lepe_w, lepe_b, lepe);
  attn_kernel<<<1024, 256, 0, stream>>>(qr, kr, vv, mask_w, v1, 0);
  attn_kernel<<<1024, 256, 0, stream>>>(qr, kr, v1, mask_h, attn_out, 1);
  out_gemm_kernel<<<512, 256, 0, stream>>>(attn_out, lepe, owT, out_b, (float*)d_out);
}

// Round 5
// 281.831 us; speedup vs baseline: 1.2773x; 1.0275x over previous
//
#include <hip/hip_runtime.h>

typedef unsigned short u16;
typedef __attribute__((ext_vector_type(4))) float f32x4;
typedef __attribute__((ext_vector_type(8))) short bf16x8;
typedef __attribute__((ext_vector_type(8))) u16 u16x8;
typedef __attribute__((ext_vector_type(4))) u16 u16x4v;

#define DI __device__ __forceinline__

DI u16 f2bf(float f) {
  unsigned int x = __float_as_uint(f);
  unsigned int r = (x + 0x7fffu + ((x >> 16) & 1u)) >> 16;
  return (u16)r;
}
DI float bf2f(u16 u) { return __uint_as_float(((unsigned int)u) << 16); }

// ---------------------------------------------------------------------------
// K0: pack weights. wqkvT[768][256] bf16 (row c = column c of [q|k*s|v]),
// bias[768] fp32 (k part pre-scaled), owT[256][256] bf16 (row c = col c of out_w)
// ---------------------------------------------------------------------------
__global__ __launch_bounds__(256) void pack_kernel(
    const float* __restrict__ qw, const float* __restrict__ qb,
    const float* __restrict__ kw, const float* __restrict__ kb,
    const float* __restrict__ vw, const float* __restrict__ vb,
    const float* __restrict__ ow,
    u16* __restrict__ wqkvT, float* __restrict__ bias, u16* __restrict__ owT)
{
  const int r = blockIdx.x;   // 0..1023
  const int t = threadIdx.x;  // 0..255
  if (r < 768) {
    const int p = r >> 8, c = r & 255;
    const float* wsrc = p == 0 ? qw : (p == 1 ? kw : vw);
    const float sc = (p == 1) ? 0.17677669529663687f : 1.0f;  // 1/sqrt(32)
    wqkvT[r * 256 + t] = f2bf(wsrc[t * 256 + c] * sc);
    if (t == 0) {
      const float* bs = p == 0 ? qb : (p == 1 ? kb : vb);
      bias[r] = bs[c] * sc;
    }
  } else {
    const int c = r - 768;
    owT[c * 256 + t] = f2bf(ow[t * 256 + c]);
  }
}

// ---------------------------------------------------------------------------
// K1a: x fp32 -> bf16, stored TILE-SWIZZLED so that a linear global_load_lds
// copy of one 128x256 tile produces an LDS image whose ds_read_b128
// A-fragment reads are bank-conflict-friendly.
// ---------------------------------------------------------------------------
__global__ __launch_bounds__(256) void convert_kernel(
    const float* __restrict__ x, u16* __restrict__ xb)
{
  const int idx = blockIdx.x * 256 + threadIdx.x;  // 0..2097151
  const int tile = idx >> 12;        // 4096 chunks of 16B per 64KB tile
  const int within = idx & 4095;
  const int r = within >> 5;         // 32 chunks per 512B row
  const int bc = (within & 31) << 4;
  const int sbc = bc ^ ((r & 7) << 4);
  const int row = (tile << 7) + r;
  const float* sp = x + row * 256 + (sbc >> 1);
  const float4 a = *reinterpret_cast<const float4*>(sp);
  const float4 b = *reinterpret_cast<const float4*>(sp + 4);
  u16x8 o;
  o[0] = f2bf(a.x); o[1] = f2bf(a.y); o[2] = f2bf(a.z); o[3] = f2bf(a.w);
  o[4] = f2bf(b.x); o[5] = f2bf(b.y); o[6] = f2bf(b.z); o[7] = f2bf(b.w);
  *reinterpret_cast<u16x8*>(xb + (idx << 3)) = o;
}

// ---------------------------------------------------------------------------
// K1b: QKV projection + bias + RoPE. Grid 512: one block per 128-row tile,
// stages the full 128x256 A-tile ONCE (64 KB LDS via global_load_lds from the
// pre-swizzled source), loops over 6 column groups. Epilogue transposes each
// wave's 16x64 output slab through a per-wave LDS buffer so each lane owns 8
// CONSECUTIVE columns: RoPE pairs are in-lane (no shfl), sin/cos are 16B
// vector loads, and stores are 16B bf16x8 (coalesced).
// ---------------------------------------------------------------------------
__global__ __launch_bounds__(256, 2) void qkv_gemm_kernel(
    const u16* __restrict__ xb, const u16* __restrict__ wT, const float* __restrict__ bias,
    const float* __restrict__ sinp, const float* __restrict__ cosp,
    u16* __restrict__ qr, u16* __restrict__ kr, u16* __restrict__ v)
{
  __shared__ u16 As[32768];        // 64 KB swizzled A-tile
  __shared__ float Tr[4][1024];    // 16 KB: per-wave 16x64 transpose slab (stride 64, g-XOR swizzle)
  const int t = threadIdx.x;
  const int wave = t >> 6, lane = t & 63;
  const int g = lane >> 4, lr = lane & 15;
  const int wr = wave >> 1, wc = wave & 1;
  const int m0 = blockIdx.x * 128;

  {
    const u16* src = xb + (size_t)blockIdx.x * 32768;
    auto gsrc = (const __attribute__((address_space(1))) u16*)src;
    auto lds = (__attribute__((address_space(3))) u16*)As;
#pragma unroll
    for (int i = 0; i < 16; ++i) {
      const int o = wave * 8192 + i * 512;  // u16 units; 1 KB per call
      __builtin_amdgcn_global_load_lds(
          (const __attribute__((address_space(1))) void*)(gsrc + o + lane * 8),
          (__attribute__((address_space(3))) void*)(lds + o), 16, 0, 0);
    }
  }
  __syncthreads();

  const char* Ab = (const char*)As;
  float* Trw = Tr[wave];
  const int tl = (lane >> 3);        // 0..7: token sub-row for epilogue reads
  const int cg8 = (lane & 7) * 8;    // 0..56: column chunk for epilogue reads

  for (int cg = 0; cg < 6; ++cg) {
    const int c0 = cg * 128;
    f32x4 acc[4][4];
#pragma unroll
    for (int i = 0; i < 4; ++i)
#pragma unroll
      for (int j = 0; j < 4; ++j) acc[i][j] = (f32x4){0.f, 0.f, 0.f, 0.f};

#pragma unroll
    for (int ks = 0; ks < 8; ++ks) {
      bf16x8 af[4], bfr[4];
#pragma unroll
      for (int mt = 0; mt < 4; ++mt) {
        const int rr = wr * 64 + mt * 16 + lr;
        const int cb = (ks * 64 + g * 16) ^ ((rr & 7) << 4);
        af[mt] = *reinterpret_cast<const bf16x8*>(Ab + rr * 512 + cb);
      }
#pragma unroll
      for (int nt = 0; nt < 4; ++nt)
        bfr[nt] = *reinterpret_cast<const bf16x8*>(wT + (c0 + wc * 64 + nt * 16 + lr) * 256 + ks * 32 + g * 8);
#pragma unroll
      for (int mt = 0; mt < 4; ++mt)
#pragma unroll
        for (int nt = 0; nt < 4; ++nt)
          acc[mt][nt] = __builtin_amdgcn_mfma_f32_16x16x32_bf16(af[mt], bfr[nt], acc[mt][nt], 0, 0, 0);
    }

    const int colb = c0 + wc * 64;
    const int proj = colb >> 8;  // 0=q 1=k 2=v (uniform per wave)
    u16* dst = proj == 0 ? qr : (proj == 1 ? kr : v);
    const int e0 = (colb & 255) + cg8;

    float bcv[4];
#pragma unroll
    for (int nt = 0; nt < 4; ++nt) bcv[nt] = bias[colb + nt * 16 + lr];

#pragma unroll
    for (int mt = 0; mt < 4; ++mt) {
      // scatter this wave's 16x64 slab into Tr: row = g*4+j, col = nt*16+lr,
      // col XOR (g<<4) keeps writes 2-way max (free).
#pragma unroll
      for (int nt = 0; nt < 4; ++nt)
#pragma unroll
        for (int j = 0; j < 4; ++j)
          Trw[(g * 4 + j) * 64 + ((nt * 16 + lr) ^ (g << 4))] = acc[mt][nt][j] + bcv[nt];
      asm volatile("s_waitcnt lgkmcnt(0)" ::: "memory");
#pragma unroll
      for (int r2 = 0; r2 < 2; ++r2) {
        const int row = tl + 8 * r2;                    // 0..15
        const int rb = row * 64 + (cg8 ^ ((row >> 2) << 4));
        const float4 v0 = *reinterpret_cast<const float4*>(Trw + rb);
        const float4 v1 = *reinterpret_cast<const float4*>(Trw + rb + 4);
        const int tok = m0 + wr * 64 + mt * 16 + row;
        float r0, r1, r2v, r3, r4, r5, r6, r7;
        if (proj < 2) {
          const int pos = tok & 4095;        // h*64 + w
          const int d0 = cg8 & 31;           // head-dim base (multiple of 8)
          const float* sp2 = sinp + pos * 32 + d0;
          const float* cp2 = cosp + pos * 32 + d0;
          const float4 s0 = *reinterpret_cast<const float4*>(sp2);
          const float4 s1 = *reinterpret_cast<const float4*>(sp2 + 4);
          const float4 cA = *reinterpret_cast<const float4*>(cp2);
          const float4 cB = *reinterpret_cast<const float4*>(cp2 + 4);
          r0  = v0.x * cA.x - v0.y * s0.x;
          r1  = v0.y * cA.y + v0.x * s0.y;
          r2v = v0.z * cA.z - v0.w * s0.z;
          r3  = v0.w * cA.w + v0.z * s0.w;
          r4  = v1.x * cB.x - v1.y * s1.x;
          r5  = v1.y * cB.y + v1.x * s1.y;
          r6  = v1.z * cB.z - v1.w * s1.z;
          r7  = v1.w * cB.w + v1.z * s1.w;
        } else {
          r0 = v0.x; r1 = v0.y; r2v = v0.z; r3 = v0.w;
          r4 = v1.x; r5 = v1.y; r6 = v1.z; r7 = v1.w;
        }
        u16x8 o;
        o[0] = f2bf(r0);  o[1] = f2bf(r1);  o[2] = f2bf(r2v); o[3] = f2bf(r3);
        o[4] = f2bf(r4);  o[5] = f2bf(r5);  o[6] = f2bf(r6);  o[7] = f2bf(r7);
        *reinterpret_cast<u16x8*>(dst + tok * 256 + e0) = o;
      }
      asm volatile("s_waitcnt lgkmcnt(0)" ::: "memory");  // drain before next mt overwrites Tr
    }
  }
}

// ---------------------------------------------------------------------------
// K2/K3: axial attention. mode 0: over W (block = (b,h), token stride 256).
//        mode 1: over H (block = (b,w), token stride 16384).
// ---------------------------------------------------------------------------
__global__ __launch_bounds__(256, 2) void attn_kernel(
    const u16* __restrict__ qr, const u16* __restrict__ kr, const u16* __restrict__ vsrc,
    const float* __restrict__ mask, u16* __restrict__ dst, const int mode)
{
  __shared__ u16 Pbuf[4][64][72];
  __shared__ u16 Vs[64][260];
  const int t = threadIdx.x;
  const int wave = t >> 6, lane = t & 63;
  const int g = lane >> 4, lr = lane & 15;
  const int b = blockIdx.x >> 6, o = blockIdx.x & 63;
  const int base = (mode == 0) ? (b * 4096 + o * 64) * 256 : (b * 4096 + o) * 256;
  const int ts = (mode == 0) ? 256 : 16384;

#pragma unroll
  for (int i = 0; i < 16; ++i) {
    const int idx = t + 256 * i;
    const int tok = idx >> 6, c4 = (idx & 63) << 2;
    *reinterpret_cast<u16x4v*>(&Vs[tok][c4]) =
        *reinterpret_cast<const u16x4v*>(vsrc + base + tok * ts + c4);
  }
  __syncthreads();

  for (int hh = 0; hh < 2; ++hh) {
    const int n = wave * 2 + hh;
    bf16x8 qf[4], kf[4];
#pragma unroll
    for (int mt = 0; mt < 4; ++mt) {
      qf[mt] = *reinterpret_cast<const bf16x8*>(qr + base + (mt * 16 + lr) * ts + n * 32 + g * 8);
      kf[mt] = *reinterpret_cast<const bf16x8*>(kr + base + (mt * 16 + lr) * ts + n * 32 + g * 8);
    }
    const f32x4 zero = (f32x4){0.f, 0.f, 0.f, 0.f};
    f32x4 s[4][4];
#pragma unroll
    for (int mt = 0; mt < 4; ++mt)
#pragma unroll
      for (int nt = 0; nt < 4; ++nt)
        s[mt][nt] = __builtin_amdgcn_mfma_f32_16x16x32_bf16(qf[mt], kf[nt], zero, 0, 0, 0);

    const float* mp = mask + n * 4096;
#pragma unroll
    for (int mt = 0; mt < 4; ++mt) {
#pragma unroll
      for (int j = 0; j < 4; ++j) {
        const int r = mt * 16 + g * 4 + j;
#pragma unroll
        for (int nt = 0; nt < 4; ++nt)
          s[mt][nt][j] += mp[r * 64 + nt * 16 + lr];
        float m = fmaxf(fmaxf(s[mt][0][j], s[mt][1][j]), fmaxf(s[mt][2][j], s[mt][3][j]));
        m = fmaxf(m, __shfl_xor(m, 1));
        m = fmaxf(m, __shfl_xor(m, 2));
        m = fmaxf(m, __shfl_xor(m, 4));
        m = fmaxf(m, __shfl_xor(m, 8));
        float sum = 0.f;
#pragma unroll
        for (int nt = 0; nt < 4; ++nt) {
          const float p = __expf(s[mt][nt][j] - m);
          s[mt][nt][j] = p;
          sum += p;
        }
        sum += __shfl_xor(sum, 1);
        sum += __shfl_xor(sum, 2);
        sum += __shfl_xor(sum, 4);
        sum += __shfl_xor(sum, 8);
        const float rs = 1.f / sum;
#pragma unroll
        for (int nt = 0; nt < 4; ++nt)
          Pbuf[wave][r][nt * 16 + lr] = f2bf(s[mt][nt][j] * rs);
      }
    }
    __syncthreads();

    f32x4 oacc[4][2];
#pragma unroll
    for (int mt = 0; mt < 4; ++mt)
#pragma unroll
      for (int nd = 0; nd < 2; ++nd) oacc[mt][nd] = zero;

#pragma unroll
    for (int kt = 0; kt < 2; ++kt) {
      bf16x8 pa[4];
#pragma unroll
      for (int mt = 0; mt < 4; ++mt)
        pa[mt] = *reinterpret_cast<const bf16x8*>(&Pbuf[wave][mt * 16 + lr][kt * 32 + g * 8]);
#pragma unroll
      for (int nd = 0; nd < 2; ++nd) {
        const int dcol = n * 32 + nd * 16 + lr;
        bf16x8 vb;
#pragma unroll
        for (int j2 = 0; j2 < 8; ++j2)
          vb[j2] = (short)Vs[kt * 32 + g * 8 + j2][dcol];
#pragma unroll
        for (int mt = 0; mt < 4; ++mt)
          oacc[mt][nd] = __builtin_amdgcn_mfma_f32_16x16x32_bf16(pa[mt], vb, oacc[mt][nd], 0, 0, 0);
      }
    }
#pragma unroll
    for (int mt = 0; mt < 4; ++mt)
#pragma unroll
      for (int nd = 0; nd < 2; ++nd)
#pragma unroll
        for (int j = 0; j < 4; ++j)
          dst[base + (mt * 16 + g * 4 + j) * ts + n * 32 + nd * 16 + lr] = f2bf(oacc[mt][nd][j]);
    __syncthreads();
  }
}

// ---------------------------------------------------------------------------
// K4: depthwise 5x5 conv (LePE). thread = 4 consecutive w-pixels x 8 channels,
// register-blocked: per dy the 8 input columns are loaded as independent 16B
// loads (MLP=8), converted once, reused across all 5 dx taps and 4 pixels.
// ---------------------------------------------------------------------------
__global__ __launch_bounds__(256) void lepe_kernel(
    const u16* __restrict__ v, const float* __restrict__ cw, const float* __restrict__ cb,
    u16* __restrict__ lepe)
{
  const int t = threadIdx.x;
  const int cg = t & 31, pg = t >> 5;     // 32 channel-groups x 8 pixel-groups
  const int c0 = cg * 8;
  const int rowi = blockIdx.x >> 1;       // b*64 + h, 0..1023
  const int w0 = (blockIdx.x & 1) * 32 + pg * 4;
  const int h = rowi & 63;

  float acc[4][8];
#pragma unroll
  for (int p = 0; p < 4; ++p)
#pragma unroll
    for (int j = 0; j < 8; ++j) acc[p][j] = 0.f;

#pragma unroll
  for (int dy = 0; dy < 5; ++dy) {
    const int hh = h + dy - 2;
    if ((unsigned)hh >= 64u) continue;
    const u16* vrow = v + (size_t)(rowi + dy - 2) * 64 * 256 + c0;
    float fin[8][8];
#pragma unroll
    for (int i = 0; i < 8; ++i) {
      const int ww = w0 - 2 + i;
      if ((unsigned)ww < 64u) {
        const u16x8 val = *reinterpret_cast<const u16x8*>(vrow + ww * 256);
#pragma unroll
        for (int j = 0; j < 8; ++j) fin[i][j] = bf2f(val[j]);
      } else {
#pragma unroll
        for (int j = 0; j < 8; ++j) fin[i][j] = 0.f;
      }
    }
#pragma unroll
    for (int dx = 0; dx < 5; ++dx) {
      const float* wp = cw + (dy * 5 + dx) * 256 + c0;
      const float4 wA = *reinterpret_cast<const float4*>(wp);
      const float4 wB = *reinterpret_cast<const float4*>(wp + 4);
      const float wv[8] = {wA.x, wA.y, wA.z, wA.w, wB.x, wB.y, wB.z, wB.w};
#pragma unroll
      for (int p = 0; p < 4; ++p)
#pragma unroll
        for (int j = 0; j < 8; ++j)
          acc[p][j] += fin[p + dx][j] * wv[j];
    }
  }

#pragma unroll
  for (int p = 0; p < 4; ++p) {
    u16x8 r;
#pragma unroll
    for (int j = 0; j < 8; ++j) r[j] = f2bf(acc[p][j] + cb[c0 + j]);
    *reinterpret_cast<u16x8*>(lepe + ((size_t)rowi * 64 + w0 + p) * 256 + c0) = r;
  }
}

// ---------------------------------------------------------------------------
// K5: out = (attn_out + lepe) @ out_w + out_b. Grid 512: stage the fused
// 128x256 A-tile once (swizzled ds_write), loop both 128-col groups.
// ---------------------------------------------------------------------------
__global__ __launch_bounds__(256, 2) void out_gemm_kernel(
    const u16* __restrict__ ao, const u16* __restrict__ lep, const u16* __restrict__ owT,
    const float* __restrict__ ob, float* __restrict__ out)
{
  __shared__ u16 As[32768];
  const int t = threadIdx.x;
  const int wave = t >> 6, lane = t & 63;
  const int g = lane >> 4, lr = lane & 15;
  const int wr = wave >> 1, wc = wave & 1;
  const int m0 = blockIdx.x * 128;

  char* Abw = (char*)As;
#pragma unroll
  for (int i = 0; i < 16; ++i) {
    const int idx = t + 256 * i;        // 16B chunk index
    const int r = idx >> 5;
    const int bc = (idx & 31) << 4;
    const int off = (m0 + r) * 256 + (bc >> 1);
    const u16x8 a = *reinterpret_cast<const u16x8*>(ao + off);
    const u16x8 l = *reinterpret_cast<const u16x8*>(lep + off);
    u16x8 s;
#pragma unroll
    for (int j = 0; j < 8; ++j) s[j] = f2bf(bf2f(a[j]) + bf2f(l[j]));
    *reinterpret_cast<u16x8*>(Abw + r * 512 + (bc ^ ((r & 7) << 4))) = s;
  }
  __syncthreads();

  const char* Ab = (const char*)As;
  for (int cg = 0; cg < 2; ++cg) {
    const int c0 = cg * 128;
    f32x4 acc[4][4];
#pragma unroll
    for (int i = 0; i < 4; ++i)
#pragma unroll
      for (int j = 0; j < 4; ++j) acc[i][j] = (f32x4){0.f, 0.f, 0.f, 0.f};

#pragma unroll
    for (int ks = 0; ks < 8; ++ks) {
      bf16x8 af[4], bfr[4];
#pragma unroll
      for (int mt = 0; mt < 4; ++mt) {
        const int rr = wr * 64 + mt * 16 + lr;
        const int cb = (ks * 64 + g * 16) ^ ((rr & 7) << 4);
        af[mt] = *reinterpret_cast<const bf16x8*>(Ab + rr * 512 + cb);
      }
#pragma unroll
      for (int nt = 0; nt < 4; ++nt)
        bfr[nt] = *reinterpret_cast<const bf16x8*>(owT + (c0 + wc * 64 + nt * 16 + lr) * 256 + ks * 32 + g * 8);
#pragma unroll
      for (int mt = 0; mt < 4; ++mt)
#pragma unroll
        for (int nt = 0; nt < 4; ++nt)
          acc[mt][nt] = __builtin_amdgcn_mfma_f32_16x16x32_bf16(af[mt], bfr[nt], acc[mt][nt], 0, 0, 0);
    }

#pragma unroll
    for (int mt = 0; mt < 4; ++mt) {
#pragma unroll
      for (int nt = 0; nt < 4; ++nt) {
        const int col = c0 + wc * 64 + nt * 16 + lr;
        const float bc2 = ob[col];
#pragma unroll
        for (int j = 0; j < 4; ++j) {
          const int tok = m0 + wr * 64 + mt * 16 + g * 4 + j;
          out[tok * 256 + col] = acc[mt][nt][j] + bc2;
        }
      }
    }
  }
}

// ---------------------------------------------------------------------------
extern "C" void kernel_launch(void* const* d_in, const int* in_sizes, int n_in,
                              void* d_out, int out_size, void* d_ws, size_t ws_size,
                              hipStream_t stream)
{
  const float* x      = (const float*)d_in[0];
  const float* sinp   = (const float*)d_in[1];
  const float* cosp   = (const float*)d_in[2];
  const float* mask_h = (const float*)d_in[3];
  const float* mask_w = (const float*)d_in[4];
  const float* q_w    = (const float*)d_in[5];
  const float* q_b    = (const float*)d_in[6];
  const float* k_w    = (const float*)d_in[7];
  const float* k_b    = (const float*)d_in[8];
  const float* v_w    = (const float*)d_in[9];
  const float* v_b    = (const float*)d_in[10];
  const float* lepe_w = (const float*)d_in[11];
  const float* lepe_b = (const float*)d_in[12];
  const float* out_w  = (const float*)d_in[13];
  const float* out_b  = (const float*)d_in[14];

  unsigned char* ws = (unsigned char*)d_ws;
  const size_t SZ = 33554432;  // 65536*256*2 bytes
  u16* qr    = (u16*)(ws);
  u16* kr    = (u16*)(ws + SZ);
  u16* vv    = (u16*)(ws + 2 * SZ);
  u16* v1    = (u16*)(ws + 3 * SZ);
  u16* xb    = (u16*)(ws + 4 * SZ);  // x as swizzled bf16; dead after qkv_gemm
  u16* lepe  = (u16*)(ws + 4 * SZ);  // reuses xb slot (written after qkv_gemm)
  u16* wqkvT = (u16*)(ws + 5 * SZ);
  u16* owT   = (u16*)(ws + 5 * SZ + 393216);
  float* bias = (float*)(ws + 5 * SZ + 393216 + 131072);
  u16* attn_out = vv;  // v is dead after conv + attnW

  pack_kernel<<<1024, 256, 0, stream>>>(q_w, q_b, k_w, k_b, v_w, v_b, out_w, wqkvT, bias, owT);
  convert_kernel<<<8192, 256, 0, stream>>>(x, xb);
  qkv_gemm_kernel<<<512, 256, 0, stream>>>(xb, wqkvT, bias, sinp, cosp, qr, kr, vv);
  lepe_kernel<<<2048, 256, 0, stream>>>(vv, lepe_w, lepe_b, lepe);
  attn_kernel<<<1024, 256, 0, stream>>>(qr, kr, vv, mask_w, v1, 0);
  attn_kernel<<<1024, 256, 0, stream>>>(qr, kr, v1, mask_h, attn_out, 1);
  out_gemm_kernel<<<512, 256, 0, stream>>>(attn_out, lepe, owT, out_b, (float*)d_out);
}

// Round 6
// 276.728 us; speedup vs baseline: 1.3009x; 1.0184x over previous
//
#include <hip/hip_runtime.h>

typedef unsigned short u16;
typedef __attribute__((ext_vector_type(4))) float f32x4;
typedef __attribute__((ext_vector_type(8))) short bf16x8;
typedef __attribute__((ext_vector_type(8))) u16 u16x8;
typedef __attribute__((ext_vector_type(4))) u16 u16x4v;

#define DI __device__ __forceinline__

DI u16 f2bf(float f) {
  unsigned int x = __float_as_uint(f);
  unsigned int r = (x + 0x7fffu + ((x >> 16) & 1u)) >> 16;
  return (u16)r;
}
DI float bf2f(u16 u) { return __uint_as_float(((unsigned int)u) << 16); }

// ---------------------------------------------------------------------------
// K0: pack weights. wqkvT[768][256] bf16 (row c = column c of [q|k*s|v]),
// bias[768] fp32 (k part pre-scaled), owT[256][256] bf16 (row c = col c of out_w)
// ---------------------------------------------------------------------------
__global__ __launch_bounds__(256) void pack_kernel(
    const float* __restrict__ qw, const float* __restrict__ qb,
    const float* __restrict__ kw, const float* __restrict__ kb,
    const float* __restrict__ vw, const float* __restrict__ vb,
    const float* __restrict__ ow,
    u16* __restrict__ wqkvT, float* __restrict__ bias, u16* __restrict__ owT)
{
  const int r = blockIdx.x;   // 0..1023
  const int t = threadIdx.x;  // 0..255
  if (r < 768) {
    const int p = r >> 8, c = r & 255;
    const float* wsrc = p == 0 ? qw : (p == 1 ? kw : vw);
    const float sc = (p == 1) ? 0.17677669529663687f : 1.0f;  // 1/sqrt(32)
    wqkvT[r * 256 + t] = f2bf(wsrc[t * 256 + c] * sc);
    if (t == 0) {
      const float* bs = p == 0 ? qb : (p == 1 ? kb : vb);
      bias[r] = bs[c] * sc;
    }
  } else {
    const int c = r - 768;
    owT[c * 256 + t] = f2bf(ow[t * 256 + c]);
  }
}

// ---------------------------------------------------------------------------
// K1: QKV projection + bias + RoPE, fused x fp32->bf16 staging.
// Grid 1024: one block per 64-row tile. Stage 64x256 A-tile (32 KB, swizzled
// reg-staged ds_write_b64), loop 6 column groups; each wave owns 32 cols.
// Epilogue: per-wave 16x36-f32 double-buffered transpose slab (stride 36 ==
// 4 mod 32 -> conflict-free float4 reads), RoPE pairs in-lane, 16B stores.
// ---------------------------------------------------------------------------
__global__ __launch_bounds__(256, 6) void qkv_gemm_kernel(
    const float* __restrict__ x, const u16* __restrict__ wT, const float* __restrict__ bias,
    const float* __restrict__ sinp, const float* __restrict__ cosp,
    u16* __restrict__ qr, u16* __restrict__ kr, u16* __restrict__ v)
{
  __shared__ u16 As[16384];        // 32 KB swizzled 64x256 bf16 tile
  __shared__ float Tr[4][2][576];  // 18 KB: per-wave dbuf 16x36 f32 slab
  const int t = threadIdx.x;
  const int wave = t >> 6, lane = t & 63;
  const int g = lane >> 4, lr = lane & 15;
  const int m0 = blockIdx.x * 64;

  {
    char* Abw = (char*)As;
#pragma unroll
    for (int i = 0; i < 16; ++i) {
      const int c = t + 256 * i;        // f32x4 chunk, 0..4095
      const int row = c >> 6, cf = c & 63;
      const float4 xv = *reinterpret_cast<const float4*>(x + (m0 + row) * 256 + cf * 4);
      u16x4v bv;
      bv.x = f2bf(xv.x); bv.y = f2bf(xv.y); bv.z = f2bf(xv.z); bv.w = f2bf(xv.w);
      *reinterpret_cast<u16x4v*>(Abw + row * 512 + ((cf * 8) ^ ((row & 7) << 4))) = bv;
    }
  }
  __syncthreads();

  const char* Ab = (const char*)As;
  const int tl8 = lane >> 2;        // 0..15: slab row for epilogue reads
  const int c8 = (lane & 3) * 8;    // 0..24: col chunk for epilogue reads

  for (int cg = 0; cg < 6; ++cg) {
    const int c0 = cg * 128;
    f32x4 acc[4][2];
#pragma unroll
    for (int i = 0; i < 4; ++i)
#pragma unroll
      for (int j = 0; j < 2; ++j) acc[i][j] = (f32x4){0.f, 0.f, 0.f, 0.f};

#pragma unroll
    for (int ks = 0; ks < 8; ++ks) {
      bf16x8 af[4], bfr[2];
#pragma unroll
      for (int mt = 0; mt < 4; ++mt) {
        const int rr = mt * 16 + lr;
        const int cb = (ks * 64 + g * 16) ^ ((rr & 7) << 4);
        af[mt] = *reinterpret_cast<const bf16x8*>(Ab + rr * 512 + cb);
      }
#pragma unroll
      for (int nt = 0; nt < 2; ++nt)
        bfr[nt] = *reinterpret_cast<const bf16x8*>(wT + (c0 + wave * 32 + nt * 16 + lr) * 256 + ks * 32 + g * 8);
#pragma unroll
      for (int mt = 0; mt < 4; ++mt)
#pragma unroll
        for (int nt = 0; nt < 2; ++nt)
          acc[mt][nt] = __builtin_amdgcn_mfma_f32_16x16x32_bf16(af[mt], bfr[nt], acc[mt][nt], 0, 0, 0);
    }

    const int colb = c0 + wave * 32;      // multiple of 32
    const int proj = colb >> 8;           // 0=q 1=k 2=v (uniform per wave)
    u16* dst = proj == 0 ? qr : (proj == 1 ? kr : v);
    const int e0 = (colb & 255) + c8;

    float bcv[2];
#pragma unroll
    for (int nt = 0; nt < 2; ++nt) bcv[nt] = bias[colb + nt * 16 + lr];

#pragma unroll
    for (int mt = 0; mt < 4; ++mt) {
      float* Trb = Tr[wave][mt & 1];
#pragma unroll
      for (int nt = 0; nt < 2; ++nt)
#pragma unroll
        for (int j = 0; j < 4; ++j)
          Trb[(g * 4 + j) * 36 + nt * 16 + lr] = acc[mt][nt][j] + bcv[nt];
      asm volatile("s_waitcnt lgkmcnt(0)" ::: "memory");
      const int rb = tl8 * 36 + c8;
      const int tok = m0 + mt * 16 + tl8;
      u16x8 o;
      if (proj < 2) {
        const int pos = tok & 4095;  // h*64 + w
        const float* sp2 = sinp + pos * 32 + c8;
        const float* cp2 = cosp + pos * 32 + c8;
        {
          const float4 v0 = *reinterpret_cast<const float4*>(Trb + rb);
          const float4 s0 = *reinterpret_cast<const float4*>(sp2);
          const float4 cA = *reinterpret_cast<const float4*>(cp2);
          o[0] = f2bf(v0.x * cA.x - v0.y * s0.x);
          o[1] = f2bf(v0.y * cA.y + v0.x * s0.y);
          o[2] = f2bf(v0.z * cA.z - v0.w * s0.z);
          o[3] = f2bf(v0.w * cA.w + v0.z * s0.w);
        }
        {
          const float4 v1 = *reinterpret_cast<const float4*>(Trb + rb + 4);
          const float4 s1 = *reinterpret_cast<const float4*>(sp2 + 4);
          const float4 cB = *reinterpret_cast<const float4*>(cp2 + 4);
          o[4] = f2bf(v1.x * cB.x - v1.y * s1.x);
          o[5] = f2bf(v1.y * cB.y + v1.x * s1.y);
          o[6] = f2bf(v1.z * cB.z - v1.w * s1.z);
          o[7] = f2bf(v1.w * cB.w + v1.z * s1.w);
        }
      } else {
        const float4 v0 = *reinterpret_cast<const float4*>(Trb + rb);
        const float4 v1 = *reinterpret_cast<const float4*>(Trb + rb + 4);
        o[0] = f2bf(v0.x); o[1] = f2bf(v0.y); o[2] = f2bf(v0.z); o[3] = f2bf(v0.w);
        o[4] = f2bf(v1.x); o[5] = f2bf(v1.y); o[6] = f2bf(v1.z); o[7] = f2bf(v1.w);
      }
      *reinterpret_cast<u16x8*>(dst + tok * 256 + e0) = o;
    }
  }
}

// ---------------------------------------------------------------------------
// K2/K3: axial attention. mode 0: over W (block = (b,h), token stride 256).
//        mode 1: over H (block = (b,w), token stride 16384).
// V staged TRANSPOSED in LDS (Vt[d][tok], tok XOR-swizzled by (d>>3)&7) so
// the PV B-fragment is one ds_read_b128. Pbuf is wave-private -> no barriers
// inside the head loop.
// ---------------------------------------------------------------------------
__global__ __launch_bounds__(256, 2) void attn_kernel(
    const u16* __restrict__ qr, const u16* __restrict__ kr, const u16* __restrict__ vsrc,
    const float* __restrict__ mask, u16* __restrict__ dst, const int mode)
{
  __shared__ u16 Pbuf[4][64][72];  // 36 KB per-wave P
  __shared__ u16 Vt[256][80];      // 40 KB transposed V (row = d, col = swizzled tok)
  const int t = threadIdx.x;
  const int wave = t >> 6, lane = t & 63;
  const int g = lane >> 4, lr = lane & 15;
  const int b = blockIdx.x >> 6, o = blockIdx.x & 63;
  const int base = (mode == 0) ? (b * 4096 + o * 64) * 256 : (b * 4096 + o) * 256;
  const int ts = (mode == 0) ? 256 : 16384;

#pragma unroll
  for (int i = 0; i < 8; ++i) {
    const int c = t + 256 * i;          // 16B chunk, 0..2047
    const int tok = c >> 5, ch = c & 31;
    const u16x8 val = *reinterpret_cast<const u16x8*>(vsrc + base + tok * ts + ch * 8);
    const int tc = tok ^ ((ch & 7) * 8);
#pragma unroll
    for (int j = 0; j < 8; ++j) Vt[ch * 8 + j][tc] = val[j];
  }
  __syncthreads();

  for (int hh = 0; hh < 2; ++hh) {
    const int n = wave * 2 + hh;
    bf16x8 qf[4], kf[4];
#pragma unroll
    for (int mt = 0; mt < 4; ++mt) {
      qf[mt] = *reinterpret_cast<const bf16x8*>(qr + base + (mt * 16 + lr) * ts + n * 32 + g * 8);
      kf[mt] = *reinterpret_cast<const bf16x8*>(kr + base + (mt * 16 + lr) * ts + n * 32 + g * 8);
    }
    const f32x4 zero = (f32x4){0.f, 0.f, 0.f, 0.f};
    f32x4 s[4][4];
#pragma unroll
    for (int mt = 0; mt < 4; ++mt)
#pragma unroll
      for (int nt = 0; nt < 4; ++nt)
        s[mt][nt] = __builtin_amdgcn_mfma_f32_16x16x32_bf16(qf[mt], kf[nt], zero, 0, 0, 0);

    const float* mp = mask + n * 4096;
#pragma unroll
    for (int mt = 0; mt < 4; ++mt) {
#pragma unroll
      for (int j = 0; j < 4; ++j) {
        const int r = mt * 16 + g * 4 + j;
#pragma unroll
        for (int nt = 0; nt < 4; ++nt)
          s[mt][nt][j] += mp[r * 64 + nt * 16 + lr];
        float m = fmaxf(fmaxf(s[mt][0][j], s[mt][1][j]), fmaxf(s[mt][2][j], s[mt][3][j]));
        m = fmaxf(m, __shfl_xor(m, 1));
        m = fmaxf(m, __shfl_xor(m, 2));
        m = fmaxf(m, __shfl_xor(m, 4));
        m = fmaxf(m, __shfl_xor(m, 8));
        float sum = 0.f;
#pragma unroll
        for (int nt = 0; nt < 4; ++nt) {
          const float p = __expf(s[mt][nt][j] - m);
          s[mt][nt][j] = p;
          sum += p;
        }
        sum += __shfl_xor(sum, 1);
        sum += __shfl_xor(sum, 2);
        sum += __shfl_xor(sum, 4);
        sum += __shfl_xor(sum, 8);
        const float rs = 1.f / sum;
#pragma unroll
        for (int nt = 0; nt < 4; ++nt)
          Pbuf[wave][r][nt * 16 + lr] = f2bf(s[mt][nt][j] * rs);
      }
    }

    f32x4 oacc[4][2];
#pragma unroll
    for (int mt = 0; mt < 4; ++mt)
#pragma unroll
      for (int nd = 0; nd < 2; ++nd) oacc[mt][nd] = zero;

#pragma unroll
    for (int kt = 0; kt < 2; ++kt) {
      bf16x8 pa[4];
#pragma unroll
      for (int mt = 0; mt < 4; ++mt)
        pa[mt] = *reinterpret_cast<const bf16x8*>(&Pbuf[wave][mt * 16 + lr][kt * 32 + g * 8]);
#pragma unroll
      for (int nd = 0; nd < 2; ++nd) {
        const int dcol = n * 32 + nd * 16 + lr;
        const bf16x8 vb = *reinterpret_cast<const bf16x8*>(
            &Vt[dcol][(kt * 32 + g * 8) ^ (((dcol >> 3) & 7) * 8)]);
#pragma unroll
        for (int mt = 0; mt < 4; ++mt)
          oacc[mt][nd] = __builtin_amdgcn_mfma_f32_16x16x32_bf16(pa[mt], vb, oacc[mt][nd], 0, 0, 0);
      }
    }
#pragma unroll
    for (int mt = 0; mt < 4; ++mt)
#pragma unroll
      for (int nd = 0; nd < 2; ++nd)
#pragma unroll
        for (int j = 0; j < 4; ++j)
          dst[base + (mt * 16 + g * 4 + j) * ts + n * 32 + nd * 16 + lr] = f2bf(oacc[mt][nd][j]);
  }
}

// ---------------------------------------------------------------------------
// K4: depthwise 5x5 conv (LePE). thread = 4 consecutive w-pixels x 8 channels.
// ---------------------------------------------------------------------------
__global__ __launch_bounds__(256) void lepe_kernel(
    const u16* __restrict__ v, const float* __restrict__ cw, const float* __restrict__ cb,
    u16* __restrict__ lepe)
{
  const int t = threadIdx.x;
  const int cg = t & 31, pg = t >> 5;     // 32 channel-groups x 8 pixel-groups
  const int c0 = cg * 8;
  const int rowi = blockIdx.x >> 1;       // b*64 + h, 0..1023
  const int w0 = (blockIdx.x & 1) * 32 + pg * 4;
  const int h = rowi & 63;

  float acc[4][8];
#pragma unroll
  for (int p = 0; p < 4; ++p)
#pragma unroll
    for (int j = 0; j < 8; ++j) acc[p][j] = 0.f;

#pragma unroll
  for (int dy = 0; dy < 5; ++dy) {
    const int hh = h + dy - 2;
    if ((unsigned)hh >= 64u) continue;
    const u16* vrow = v + (size_t)(rowi + dy - 2) * 64 * 256 + c0;
    float fin[8][8];
#pragma unroll
    for (int i = 0; i < 8; ++i) {
      const int ww = w0 - 2 + i;
      if ((unsigned)ww < 64u) {
        const u16x8 val = *reinterpret_cast<const u16x8*>(vrow + ww * 256);
#pragma unroll
        for (int j = 0; j < 8; ++j) fin[i][j] = bf2f(val[j]);
      } else {
#pragma unroll
        for (int j = 0; j < 8; ++j) fin[i][j] = 0.f;
      }
    }
#pragma unroll
    for (int dx = 0; dx < 5; ++dx) {
      const float* wp = cw + (dy * 5 + dx) * 256 + c0;
      const float4 wA = *reinterpret_cast<const float4*>(wp);
      const float4 wB = *reinterpret_cast<const float4*>(wp + 4);
      const float wv[8] = {wA.x, wA.y, wA.z, wA.w, wB.x, wB.y, wB.z, wB.w};
#pragma unroll
      for (int p = 0; p < 4; ++p)
#pragma unroll
        for (int j = 0; j < 8; ++j)
          acc[p][j] += fin[p + dx][j] * wv[j];
    }
  }

#pragma unroll
  for (int p = 0; p < 4; ++p) {
    u16x8 r;
#pragma unroll
    for (int j = 0; j < 8; ++j) r[j] = f2bf(acc[p][j] + cb[c0 + j]);
    *reinterpret_cast<u16x8*>(lepe + ((size_t)rowi * 64 + w0 + p) * 256 + c0) = r;
  }
}

// ---------------------------------------------------------------------------
// K5: out = (attn_out + lepe) @ out_w + out_b. Grid 1024: 64-row tiles,
// fused add reg-staged into swizzled 32 KB LDS; wave owns 32 cols per cg.
// ---------------------------------------------------------------------------
__global__ __launch_bounds__(256, 6) void out_gemm_kernel(
    const u16* __restrict__ ao, const u16* __restrict__ lep, const u16* __restrict__ owT,
    const float* __restrict__ ob, float* __restrict__ out)
{
  __shared__ u16 As[16384];  // 32 KB
  const int t = threadIdx.x;
  const int wave = t >> 6, lane = t & 63;
  const int g = lane >> 4, lr = lane & 15;
  const int m0 = blockIdx.x * 64;

  char* Abw = (char*)As;
#pragma unroll
  for (int i = 0; i < 8; ++i) {
    const int c = t + 256 * i;          // 16B chunk, 0..2047
    const int row = c >> 5, bc = (c & 31) << 4;
    const int off = (m0 + row) * 256 + (c & 31) * 8;
    const u16x8 a = *reinterpret_cast<const u16x8*>(ao + off);
    const u16x8 l = *reinterpret_cast<const u16x8*>(lep + off);
    u16x8 s;
#pragma unroll
    for (int j = 0; j < 8; ++j) s[j] = f2bf(bf2f(a[j]) + bf2f(l[j]));
    *reinterpret_cast<u16x8*>(Abw + row * 512 + (bc ^ ((row & 7) << 4))) = s;
  }
  __syncthreads();

  const char* Ab = (const char*)As;
  for (int cg = 0; cg < 2; ++cg) {
    const int c0 = cg * 128 + wave * 32;
    f32x4 acc[4][2];
#pragma unroll
    for (int i = 0; i < 4; ++i)
#pragma unroll
      for (int j = 0; j < 2; ++j) acc[i][j] = (f32x4){0.f, 0.f, 0.f, 0.f};

#pragma unroll
    for (int ks = 0; ks < 8; ++ks) {
      bf16x8 af[4], bfr[2];
#pragma unroll
      for (int mt = 0; mt < 4; ++mt) {
        const int rr = mt * 16 + lr;
        const int cb = (ks * 64 + g * 16) ^ ((rr & 7) << 4);
        af[mt] = *reinterpret_cast<const bf16x8*>(Ab + rr * 512 + cb);
      }
#pragma unroll
      for (int nt = 0; nt < 2; ++nt)
        bfr[nt] = *reinterpret_cast<const bf16x8*>(owT + (c0 + nt * 16 + lr) * 256 + ks * 32 + g * 8);
#pragma unroll
      for (int mt = 0; mt < 4; ++mt)
#pragma unroll
        for (int nt = 0; nt < 2; ++nt)
          acc[mt][nt] = __builtin_amdgcn_mfma_f32_16x16x32_bf16(af[mt], bfr[nt], acc[mt][nt], 0, 0, 0);
    }

#pragma unroll
    for (int mt = 0; mt < 4; ++mt) {
#pragma unroll
      for (int nt = 0; nt < 2; ++nt) {
        const int col = c0 + nt * 16 + lr;
        const float bc2 = ob[col];
#pragma unroll
        for (int j = 0; j < 4; ++j) {
          const int tok = m0 + mt * 16 + g * 4 + j;
          out[tok * 256 + col] = acc[mt][nt][j] + bc2;
        }
      }
    }
  }
}

// ---------------------------------------------------------------------------
extern "C" void kernel_launch(void* const* d_in, const int* in_sizes, int n_in,
                              void* d_out, int out_size, void* d_ws, size_t ws_size,
                              hipStream_t stream)
{
  const float* x      = (const float*)d_in[0];
  const float* sinp   = (const float*)d_in[1];
  const float* cosp   = (const float*)d_in[2];
  const float* mask_h = (const float*)d_in[3];
  const float* mask_w = (const float*)d_in[4];
  const float* q_w    = (const float*)d_in[5];
  const float* q_b    = (const float*)d_in[6];
  const float* k_w    = (const float*)d_in[7];
  const float* k_b    = (const float*)d_in[8];
  const float* v_w    = (const float*)d_in[9];
  const float* v_b    = (const float*)d_in[10];
  const float* lepe_w = (const float*)d_in[11];
  const float* lepe_b = (const float*)d_in[12];
  const float* out_w  = (const float*)d_in[13];
  const float* out_b  = (const float*)d_in[14];

  unsigned char* ws = (unsigned char*)d_ws;
  const size_t SZ = 33554432;  // 65536*256*2 bytes
  u16* qr    = (u16*)(ws);
  u16* kr    = (u16*)(ws + SZ);
  u16* vv    = (u16*)(ws + 2 * SZ);
  u16* v1    = (u16*)(ws + 3 * SZ);
  u16* lepe  = (u16*)(ws + 4 * SZ);
  u16* wqkvT = (u16*)(ws + 5 * SZ);
  u16* owT   = (u16*)(ws + 5 * SZ + 393216);
  float* bias = (float*)(ws + 5 * SZ + 393216 + 131072);
  u16* attn_out = vv;  // v is dead after conv + attnW

  pack_kernel<<<1024, 256, 0, stream>>>(q_w, q_b, k_w, k_b, v_w, v_b, out_w, wqkvT, bias, owT);
  qkv_gemm_kernel<<<1024, 256, 0, stream>>>(x, wqkvT, bias, sinp, cosp, qr, kr, vv);
  lepe_kernel<<<2048, 256, 0, stream>>>(vv, lepe_w, lepe_b, lepe);
  attn_kernel<<<1024, 256, 0, stream>>>(qr, kr, vv, mask_w, v1, 0);
  attn_kernel<<<1024, 256, 0, stream>>>(qr, kr, v1, mask_h, attn_out, 1);
  out_gemm_kernel<<<1024, 256, 0, stream>>>(attn_out, lepe, owT, out_b, (float*)d_out);
}